// Round 1
// baseline (150.513 us; speedup 1.0000x reference)
//
#include <hip/hip_runtime.h>

// Per-batch confusion-matrix histogram:
//   gt  = trunc(segmap * 255.0f)            (f32 math, matches numpy/jax)
//   keep: gt != ignore (ignore = n_classes when use_dont_care else -1)
//   hist[b][pred][gt] += 1
//
// B=64, H=W=512, NC=19 -> out_size = 64*361 = 23104 int32.
// 134 MB input reads; roofline ~15-21 us (half is L3-resident).
//
// V2: attack LDS-atomic serialization + load-latency exposure.
//  - 32-way bank-exclusive replicated LDS hist: lane l -> copy (l&31) at word
//    addr bin*32+copy => bank == copy, so a wave's 64-lane scatter NEVER has
//    a >2-way bank conflict regardless of bin distribution.
//  - 1024-thread blocks, 46.2 KB LDS, grid 512 = exactly 2 blocks/CU
//    (92 KB of 160 KB LDS, 32 waves/CU static occupancy).
//  - 4x unrolled main loop: 8 KB of loads in flight per wave.

#define NC2_MAX 361  // 19*19 for this instance
#define NREP    32   // replicas; copy c lives entirely in LDS bank c

__global__ __launch_bounds__(256) void zero_out_kernel(int* __restrict__ out, int n) {
    int i = blockIdx.x * 256 + threadIdx.x;
    if (i < n) out[i] = 0;
}

__global__ __launch_bounds__(1024, 8) void seg_hist_kernel(
    const int* __restrict__ pred,
    const float* __restrict__ seg,
    const int* __restrict__ ncls_p,
    const int* __restrict__ udc_p,
    int* __restrict__ out,
    int npix_per_batch,       // 262144
    int blocks_per_batch)     // gridDim.x
{
    __shared__ int hist[NC2_MAX * NREP];  // 46208 B

    const int nc     = ncls_p[0];
    const int nc2    = nc * nc;
    const int ignore = udc_p[0] ? nc : -1;

    const int b   = blockIdx.y;
    const int tid = threadIdx.x;
    const int rep = tid & (NREP - 1);   // lane & 31 -> private bank

    // zero LDS histogram (11552 words / 1024 threads)
    for (int i = tid; i < NC2_MAX * NREP; i += 1024) hist[i] = 0;
    __syncthreads();

    const size_t base = (size_t)b * (size_t)npix_per_batch;
    const int4*   p4 = (const int4*)(pred + base);
    const float4* s4 = (const float4*)(seg + base);
    const int nvec   = npix_per_batch >> 2;        // 65536
    const int stride = blocks_per_batch << 10;     // blocks_per_batch * 1024

#define PROC(p, s)                                                                 \
    do {                                                                           \
        int g0 = (int)((s).x * 255.0f);                                            \
        int g1 = (int)((s).y * 255.0f);                                            \
        int g2 = (int)((s).z * 255.0f);                                            \
        int g3 = (int)((s).w * 255.0f);                                            \
        if (g0 != ignore) { int bin = (p).x * nc + g0;                             \
            if ((unsigned)bin < (unsigned)nc2) atomicAdd(&hist[bin * NREP + rep], 1); } \
        if (g1 != ignore) { int bin = (p).y * nc + g1;                             \
            if ((unsigned)bin < (unsigned)nc2) atomicAdd(&hist[bin * NREP + rep], 1); } \
        if (g2 != ignore) { int bin = (p).z * nc + g2;                             \
            if ((unsigned)bin < (unsigned)nc2) atomicAdd(&hist[bin * NREP + rep], 1); } \
        if (g3 != ignore) { int bin = (p).w * nc + g3;                             \
            if ((unsigned)bin < (unsigned)nc2) atomicAdd(&hist[bin * NREP + rep], 1); } \
    } while (0)

    // grid-stride over this batch's vectorized pixels, unrolled 4x so 8 loads
    // (8 KB/wave) are in flight before any use. With blocks_per_batch=8 and
    // 1024 threads, each thread runs exactly 8 iterations = 2 unrolled chunks.
    int i = blockIdx.x * 1024 + tid;
    for (; i + 3 * stride < nvec; i += 4 * stride) {
        int4   pa = p4[i];
        int4   pb = p4[i +     stride];
        int4   pc = p4[i + 2 * stride];
        int4   pd = p4[i + 3 * stride];
        float4 sa = s4[i];
        float4 sb = s4[i +     stride];
        float4 sc = s4[i + 2 * stride];
        float4 sd = s4[i + 3 * stride];
        PROC(pa, sa);
        PROC(pb, sb);
        PROC(pc, sc);
        PROC(pd, sd);
    }
    for (; i < nvec; i += stride) {   // tail (empty for the shipped config)
        int4 p = p4[i];
        float4 s = s4[i];
        PROC(p, s);
    }
#undef PROC

    __syncthreads();

    // reduce the 32 copies and flush to global. Rotated copy index keeps the
    // 32 reads per bin conflict-free across lanes (lane t step k hits bank
    // (t+k)&31 -> all distinct within a wave-half).
    int* gout = out + (size_t)b * (size_t)nc2;
    for (int bin = tid; bin < nc2; bin += 1024) {
        int sum = 0;
        #pragma unroll
        for (int k = 0; k < NREP; ++k) {
            sum += hist[bin * NREP + ((tid + k) & (NREP - 1))];
        }
        atomicAdd(&gout[bin], sum);
    }
}

extern "C" void kernel_launch(void* const* d_in, const int* in_sizes, int n_in,
                              void* d_out, int out_size, void* d_ws, size_t ws_size,
                              hipStream_t stream) {
    const int*   pred = (const int*)d_in[0];
    const float* seg  = (const float*)d_in[1];
    const int*   ncp  = (const int*)d_in[2];
    const int*   udp  = (const int*)d_in[3];
    int* out = (int*)d_out;

    const int total_pix = in_sizes[0];         // B*H*W = 16777216
    const int B = out_size / 361;              // 64 (instance-fixed nc=19)
    const int npix_per_batch = total_pix / B;  // 262144

    // zero the output (harness poisons d_out with 0xAA before every launch)
    {
        int nblk = (out_size + 255) / 256;
        zero_out_kernel<<<nblk, 256, 0, stream>>>(out, out_size);
    }

    // 8 blocks/batch * 64 batches = 512 blocks of 1024 threads
    //   = exactly 2 blocks/CU (92 KB LDS of 160 KB), 32 waves/CU.
    const int blocks_per_batch = 8;
    dim3 grid(blocks_per_batch, B);
    seg_hist_kernel<<<grid, 1024, 0, stream>>>(pred, seg, ncp, udp, out,
                                               npix_per_batch, blocks_per_batch);
}